// Round 10
// baseline (269.136 us; speedup 1.0000x reference)
//
#include <hip/hip_runtime.h>
#include <stdint.h>

typedef __bf16 bf16_t;
typedef __bf16 bf16x8 __attribute__((ext_vector_type(8)));
typedef float f32x4 __attribute__((ext_vector_type(4)));
typedef float f32x16 __attribute__((ext_vector_type(16)));
typedef unsigned int u32x2 __attribute__((ext_vector_type(2)));

#define DEV __device__ __forceinline__

DEV void gload_lds16(const void* g, void* lds) {
  __builtin_amdgcn_global_load_lds(
      (const __attribute__((address_space(1))) uint32_t*)g,
      (__attribute__((address_space(3))) uint32_t*)lds, 16, 0, 0);
}

DEV float fexp2(float x) {
#if __has_builtin(__builtin_amdgcn_exp2f)
  return __builtin_amdgcn_exp2f(x);
#else
  return exp2f(x);
#endif
}

DEV uint32_t pk_bf16(float a, float b) {
  uint32_t lo = (uint32_t)__builtin_bit_cast(uint16_t, (bf16_t)a);
  uint32_t hi = (uint32_t)__builtin_bit_cast(uint16_t, (bf16_t)b);
  return lo | (hi << 16);
}

// -------------------------------------- K0: merged cvt (hs->bf16, W->WT, tickets)
// blocks 0..3071: hs fp32 -> bf16 (block 0 also zeroes ALL 384 combine tickets)
// blocks 3072..4799: W[k][n] (x3) -> WT[n][k] bf16
__global__ __launch_bounds__(256) void cvt(const float* __restrict__ x,
                                           bf16_t* __restrict__ y,
                                           const float* __restrict__ Wq,
                                           const float* __restrict__ Wk,
                                           const float* __restrict__ Wv,
                                           bf16_t* __restrict__ WT,
                                           uint32_t* __restrict__ tk) {
  __shared__ float T[32][36];
  const int bid = blockIdx.x;
  const int t = threadIdx.x;
  if (bid < 3072) {
    if (bid == 0) {  // ROUND-9 FIX: 384 tickets, 256 threads -> strided loop
      for (int i = t; i < 384; i += 256) tk[i] = 0;
    }
    int i = bid * 256 + t;
    float4 v = ((const float4*)x)[i];
    ((uint2*)y)[i] = make_uint2(pk_bf16(v.x, v.y), pk_bf16(v.z, v.w));
  } else {
    const int b2 = bid - 3072;
    const int bx = b2 % 72;   // n tile 0..71 (over 2304)
    const int by = b2 / 72;   // k tile 0..23 (over 768)
    const int p = bx / 24;
    const float* W = (p == 0) ? Wq : ((p == 1) ? Wk : Wv);
    const int n0 = bx * 32, nn0 = n0 - p * 768, k0 = by * 32;
    {
      int r = t >> 3, c4 = (t & 7) * 4;
      float4 v = *(const float4*)&W[(size_t)(k0 + r) * 768 + nn0 + c4];
      T[r][c4 + 0] = v.x; T[r][c4 + 1] = v.y; T[r][c4 + 2] = v.z; T[r][c4 + 3] = v.w;
    }
    __syncthreads();
    {
      int nr = t >> 3, kc = (t & 7) * 4;
      uint32_t lo = pk_bf16(T[kc + 0][nr], T[kc + 1][nr]);
      uint32_t hi = pk_bf16(T[kc + 2][nr], T[kc + 3][nr]);
      *(uint2*)&WT[(size_t)(n0 + nr) * 768 + k0 + kc] = make_uint2(lo, hi);
    }
  }
}

// ------------------------------------------------- K2: C[4096,2304] = A @ W (+b)
// K-projection output is pre-scaled by log2(e)/8 (softmax scale folded in).
// v4 = BK=64 dbuf (round-3 win) + T2 XOR-swizzle (round-8: neutral, kept).
__global__ __launch_bounds__(256) void gemm_qkv(
    const bf16_t* __restrict__ A, const bf16_t* __restrict__ Wt,
    const float* __restrict__ bq, const float* __restrict__ bk,
    const float* __restrict__ bv, bf16_t* __restrict__ Qo,
    bf16_t* __restrict__ Ko, bf16_t* __restrict__ VTo) {
  __shared__ __align__(16) char smem[65536];  // 2 x (As 16K + Bs 16K); Cs union
  bf16_t* Cs = (bf16_t*)smem;  // 128x136 epilogue scratch
  const int bx = blockIdx.x;  // 0..17 (n)
  const int by = blockIdx.y;  // 0..31 (m)
  const int m0 = by * 128, n0 = bx * 128;
  const int tid = threadIdx.x, w = tid >> 6, lane = tid & 63;
  const int mw = (w & 1) * 64, nw = (w >> 1) * 64;
  const int quad = lane >> 4, col = lane & 15;

  f32x4 acc[4][4];
  for (int i = 0; i < 4; i++)
    for (int j = 0; j < 4; j++) acc[i][j] = (f32x4){0.f, 0.f, 0.f, 0.f};

  const int srow = w * 32 + (lane >> 3);
  const int scol = ((lane & 7) ^ ((lane >> 3) & 7)) * 8;
  const bf16_t* ag = A + (size_t)(m0 + srow) * 768 + scol;
  const bf16_t* bg = Wt + (size_t)(n0 + srow) * 768 + scol;

  auto stageg = [&](int kk, int bf) {
    const int k0 = kk * 64;
    bf16_t* dA = (bf16_t*)(smem + bf * 32768) + (w * 32) * 64;
    bf16_t* dB = (bf16_t*)(smem + bf * 32768 + 16384) + (w * 32) * 64;
#pragma unroll
    for (int i = 0; i < 4; i++) {
      gload_lds16(ag + (size_t)i * 8 * 768 + k0, dA + i * 8 * 64);
      gload_lds16(bg + (size_t)i * 8 * 768 + k0, dB + i * 8 * 64);
    }
  };

  stageg(0, 0);
  __syncthreads();  // one exposed drain at prologue only

  for (int kk = 0; kk < 12; ++kk) {
    const int bf = kk & 1;
    if (kk < 11) stageg(kk + 1, bf ^ 1);
    __builtin_amdgcn_sched_barrier(0);  // pin load issue ahead of compute
    const bf16_t* As = (const bf16_t*)(smem + bf * 32768);
    const bf16_t* Bs = (const bf16_t*)(smem + bf * 32768 + 16384);
#pragma unroll
    for (int ks = 0; ks < 2; ++ks) {
      bf16x8 af[4], bfr[4];
#pragma unroll
      for (int mt = 0; mt < 4; ++mt) {
        int row = mw + mt * 16 + col;
        af[mt] = *(const bf16x8*)&As[row * 64 + (((ks * 4 + quad) ^ (row & 7)) * 8)];
      }
#pragma unroll
      for (int nt = 0; nt < 4; ++nt) {
        int row = nw + nt * 16 + col;
        bfr[nt] = *(const bf16x8*)&Bs[row * 64 + (((ks * 4 + quad) ^ (row & 7)) * 8)];
      }
#pragma unroll
      for (int mt = 0; mt < 4; ++mt)
#pragma unroll
        for (int nt = 0; nt < 4; ++nt)
          acc[mt][nt] = __builtin_amdgcn_mfma_f32_16x16x32_bf16(
              af[mt], bfr[nt], acc[mt][nt], 0, 0, 0);
    }
    __syncthreads();  // publishes stage(kk+1); all reads of buf done
  }

  const int p = bx / 6;
  const float* bp = (p == 0) ? bq : ((p == 1) ? bk : bv);
  const float kscale = (p == 1) ? 0.18033688011112042f : 1.0f;  // log2(e)/sqrt(64)
  const int bb0 = m0 >> 11, s0 = m0 & 2047;
  if (p < 2) {
#pragma unroll
    for (int nt = 0; nt < 4; nt++) {
      int n = nw + nt * 16 + col;
      float bias = bp[n0 + n - p * 768];
#pragma unroll
      for (int mt = 0; mt < 4; mt++)
#pragma unroll
        for (int r = 0; r < 4; r++) {
          int m = mw + mt * 16 + quad * 4 + r;
          Cs[m * 136 + n] = (bf16_t)((acc[mt][nt][r] + bias) * kscale);
        }
    }
    __syncthreads();
    bf16_t* dst = (p == 0) ? Qo : Ko;
#pragma unroll
    for (int i = 0; i < 8; i++) {
      int idx = i * 256 + tid;
      int m = idx >> 4, c = idx & 15;
      bf16x8 v = *(const bf16x8*)&Cs[m * 136 + c * 8];
      int nn = n0 - p * 768 + c * 8;
      int hq = nn >> 6, hd = nn & 63;
      *(bf16x8*)&dst[(size_t)((bb0 * 12 + hq) * 2048 + s0 + m) * 64 + hd] = v;
    }
  } else {
#pragma unroll
    for (int nt = 0; nt < 4; nt++) {
      int n = nw + nt * 16 + col;
      float bias = bp[n0 + n - 1536];
#pragma unroll
      for (int mt = 0; mt < 4; mt++)
#pragma unroll
        for (int r = 0; r < 4; r++) {
          int m = mw + mt * 16 + quad * 4 + r;
          Cs[n * 136 + m] = (bf16_t)(acc[mt][nt][r] + bias);
        }
    }
    __syncthreads();
#pragma unroll
    for (int i = 0; i < 8; i++) {
      int idx = i * 256 + tid;
      int n = idx >> 4, c = idx & 15;
      bf16x8 v = *(const bf16x8*)&Cs[n * 136 + c * 8];
      int nn = n0 - 1536 + n;
      int hq = nn >> 6, hd = nn & 63;
      *(bf16x8*)&VTo[((size_t)(bb0 * 12 + hq) * 64 + hd) * 2048 + s0 + c * 8] = v;
    }
  }
}

// ---------------------------------------------------------------- K3: attention
// v11b = v7 main loop (round-3 best; do not restructure) + fused split-K
// combine. ROUND-9 FIXES: (1) all 384 tickets now zeroed (was 256 -> bh>=16
// tiles never finalized); (2) __syncthreads() between the partial-store
// release fence and the tid0 ticket bump (was racy: wave 0 could bump before
// waves 1-3 finished their partial stores).
__global__ __launch_bounds__(256, 3) void attn(const bf16_t* __restrict__ Q,
                                               const bf16_t* __restrict__ K,
                                               const bf16_t* __restrict__ VT,
                                               float* __restrict__ Op,
                                               float* __restrict__ lp,
                                               float* __restrict__ out,
                                               uint32_t* __restrict__ tk) {
  __shared__ __align__(16) char smem[49152];
  bf16_t* Kl = (bf16_t*)smem;            // [3][64*64], XOR-swizzled by row&7
  bf16_t* Vl = (bf16_t*)(smem + 24576);  // [3][64*64], same swizzle
  const int id = blockIdx.x;             // 0..767
  const int rr0 = id >> 3;               // 0..95
  const int bh = (id & 7) * 3 + (rr0 >> 5);  // XCD id&7 owns 3 consecutive bh
  const int w5 = rr0 & 31;
  const int qt = w5 & 15, sp = w5 >> 4;  // q-tile, key-split half
  const int tid = threadIdx.x, wv = tid >> 6, lane = tid & 63;
  const int lq = lane & 31, half = lane >> 5;
  const int q0 = qt * 128 + wv * 32;

  bf16x8 qf[4];  // B-frags of Q^T (per-lane query = lq), register resident
#pragma unroll
  for (int ks = 0; ks < 4; ++ks)
    qf[ks] = *(const bf16x8*)&Q[(size_t)(bh * 2048 + q0 + lq) * 64 + ks * 16 + half * 8];

  f32x16 oacc[2];  // O^T partial: col=q (lane), rows=d
  for (int i = 0; i < 16; i++) { oacc[0][i] = 0.f; oacc[1][i] = 0.f; }
  float l0 = 0.f, l1 = 0.f, l2 = 0.f, l3 = 0.f;  // partial denominators

  const bf16_t* gK = K + (size_t)bh * 2048 * 64 + (size_t)sp * 1024 * 64;
  const bf16_t* gV = VT + (size_t)bh * 64 * 2048 + sp * 1024;
  const int srow = lane >> 3, scc = lane & 7;
  const int cg = scc ^ srow;  // inverse-swizzled source col (row&7 == srow)
  const bf16_t* gKb = gK + srow * 64 + cg * 8;    // + kb*4096 + ii*512
  const bf16_t* gVb = gV + srow * 2048 + cg * 8;  // + ii*16384 + kb*64
  const int kpart = (wv & 1) * 4;  // waves 0,1 stage K chunks 0-3/4-7; 2,3 V

  auto stage = [&](int kb, int buf) {
    if (wv < 2) {
#pragma unroll
      for (int i = 0; i < 4; i++) {
        int ii = kpart + i;
        gload_lds16(gKb + kb * 4096 + ii * 512, Kl + buf * 4096 + ii * 512);
      }
    } else {
#pragma unroll
      for (int i = 0; i < 4; i++) {
        int ii = kpart + i;
        gload_lds16(gVb + (size_t)ii * 16384 + kb * 64, Vl + buf * 4096 + ii * 512);
      }
    }
  };

  stage(0, 0);
  stage(1, 1);
  asm volatile("s_waitcnt vmcnt(4)" ::: "memory");  // buf0 (+Q) done; buf1 flying
  __builtin_amdgcn_s_barrier();
  asm volatile("" ::: "memory");

  int bb = 0, rb = 2;
  for (int kb = 0; kb < 16; ++kb) {
    if (kb < 14) stage(kb + 2, rb);  // 2-deep prefetch, in flight across barriers

    // S^T[key][q] = K_blk @ Q^T   (K pre-scaled by log2e/8 at projection)
    f32x16 sacc[2];
    for (int i = 0; i < 16; i++) { sacc[0][i] = 0.f; sacc[1][i] = 0.f; }
    __builtin_amdgcn_s_setprio(1);
#pragma unroll
    for (int t = 0; t < 2; t++) {
      const int row = t * 32 + lq;
#pragma unroll
      for (int ks = 0; ks < 4; ++ks) {
        bf16x8 kf = *(const bf16x8*)&Kl[bb * 4096 + row * 64 + (((2 * ks + half) ^ (row & 7)) * 8)];
        sacc[t] = __builtin_amdgcn_mfma_f32_32x32x16_bf16(kf, qf[ks], sacc[t], 0, 0, 0);
      }
    }
    __builtin_amdgcn_s_setprio(0);

    // P = exp2(S) (fixed max), l in 4 partial chains
#pragma unroll
    for (int t = 0; t < 2; t++)
#pragma unroll
      for (int rr = 0; rr < 16; rr++) sacc[t][rr] = fexp2(sacc[t][rr]);
#pragma unroll
    for (int rr = 0; rr < 16; rr += 4) {
      l0 += sacc[0][rr + 0] + sacc[1][rr + 0];
      l1 += sacc[0][rr + 1] + sacc[1][rr + 1];
      l2 += sacc[0][rr + 2] + sacc[1][rr + 2];
      l3 += sacc[0][rr + 3] + sacc[1][rr + 3];
    }

    // pack quads: pkq[t][g] = keys t*32 + 8g + 4*half + {0..3}, as 2x u32
    uint32_t pkq[2][4][2];
#pragma unroll
    for (int t = 0; t < 2; t++)
#pragma unroll
      for (int g = 0; g < 4; g++) {
        pkq[t][g][0] = pk_bf16(sacc[t][4 * g + 0], sacc[t][4 * g + 1]);
        pkq[t][g][1] = pk_bf16(sacc[t][4 * g + 2], sacc[t][4 * g + 3]);
      }

    // cross-half exchange -> B-operand frags via permlane32_swap
    bf16x8 pfrag[4];
#pragma unroll
    for (int t = 0; t < 2; t++)
#pragma unroll
      for (int e = 0; e < 2; e++) {
        union { uint32_t u[4]; bf16x8 v; } F;
#pragma unroll
        for (int wd = 0; wd < 2; wd++) {
#if __has_builtin(__builtin_amdgcn_permlane32_swap)
          u32x2 sw = __builtin_amdgcn_permlane32_swap(pkq[t][2 * e][wd],
                                                      pkq[t][2 * e + 1][wd],
                                                      false, false);
          F.u[wd] = sw.x;
          F.u[2 + wd] = sw.y;
#else
          uint32_t s = half ? pkq[t][2 * e][wd] : pkq[t][2 * e + 1][wd];
          uint32_t rx = __shfl_xor(s, 32);
          uint32_t ow = half ? pkq[t][2 * e + 1][wd] : pkq[t][2 * e][wd];
          F.u[wd] = half ? rx : ow;
          F.u[2 + wd] = half ? ow : rx;
#endif
        }
        pfrag[2 * t + e] = F.v;
      }

    // O^T += V^T @ P^T  (A = V frags from LDS, B = pfrag)
    __builtin_amdgcn_s_setprio(1);
#pragma unroll
    for (int c = 0; c < 4; c++) {
#pragma unroll
      for (int dt = 0; dt < 2; dt++) {
        const int vr = dt * 32 + lq;
        bf16x8 vf = *(const bf16x8*)&Vl[bb * 4096 + vr * 64 + (((2 * c + half) ^ (vr & 7)) * 8)];
        oacc[dt] = __builtin_amdgcn_mfma_f32_32x32x16_bf16(vf, pfrag[c], oacc[dt], 0, 0, 0);
      }
    }
    __builtin_amdgcn_s_setprio(0);

    // counted wait: keep newest stage batch (4 loads/wave) in flight
    if (kb < 14) {
      asm volatile("s_waitcnt vmcnt(4)" ::: "memory");
    } else if (kb == 14) {
      asm volatile("s_waitcnt vmcnt(0)" ::: "memory");
    }
    if (kb < 15) {
      __builtin_amdgcn_s_barrier();
      asm volatile("" ::: "memory");
    }
    bb = (bb == 2) ? 0 : bb + 1;
    rb = (rb == 2) ? 0 : rb + 1;
  }

  // epilogue: partial l + unnormalized partial O^T -> Op[q][d] rows
  float l_own = (l0 + l1) + (l2 + l3);
  float l_tot = l_own + __shfl_xor(l_own, 32);
  __syncthreads();  // all K/V reads done; smem becomes 4x 8KB f32 scratch
  float* Of = (float*)smem + wv * 2048;
#pragma unroll
  for (int dt = 0; dt < 2; dt++)
#pragma unroll
    for (int rr = 0; rr < 16; rr++) {
      int d = dt * 32 + (rr & 3) + 8 * (rr >> 2) + 4 * half;
      int g = d >> 2, wd = d & 3;
      Of[lq * 64 + ((g ^ (lq & 15)) * 4) + wd] = oacc[dt][rr];
    }
  if (half == 0) lp[((size_t)sp * 24 + bh) * 2048 + q0 + lq] = l_tot;
  float* ob = Op + (((size_t)sp * 24 + bh) * 2048 + q0) * 64;
#pragma unroll
  for (int i = 0; i < 8; i++) {
    int idx = i * 64 + lane;
    int qq = idx >> 4, c = idx & 15;
    f32x4 v = *(f32x4*)&Of[qq * 64 + ((c ^ (qq & 15)) * 4)];
    *(f32x4*)&ob[(size_t)qq * 64 + c * 4] = v;
  }

  // ---- fused split-K combine: second arriver of this (bh,qt) finalizes ----
  __threadfence();       // release this thread's partial O + l (device scope)
  __syncthreads();       // ROUND-9 FIX: all waves' partials stored+fenced
  int* flagp = (int*)(smem + 49144);
  if (tid == 0) *flagp = (int)atomicAdd(&tk[bh * 16 + qt], 1u);
  __syncthreads();
  if (*flagp == 1) {
    __threadfence();  // acquire other block's partial
    const int b = bh / 12, head = bh % 12;
    const size_t plane = (size_t)24 * 2048 * 64;
    const float* O0 = Op + (((size_t)bh * 2048) + q0) * 64;           // sp=0
    const float* O1 = Op + plane + (((size_t)bh * 2048) + q0) * 64;   // sp=1
    const float* lp0 = lp + (size_t)bh * 2048 + q0;
    const float* lp1 = lp + (size_t)24 * 2048 + (size_t)bh * 2048 + q0;
    float* ob2 = out + ((size_t)b * 2048 + q0) * 768 + head * 64;
#pragma unroll
    for (int i = 0; i < 8; i++) {
      int idx = i * 64 + lane;
      int qq = idx >> 4, c = idx & 15;
      f32x4 a = *(const f32x4*)&O0[(size_t)qq * 64 + c * 4];
      f32x4 d = *(const f32x4*)&O1[(size_t)qq * 64 + c * 4];
      float inv = 1.0f / (lp0[qq] + lp1[qq]);
      f32x4 r;
#pragma unroll
      for (int j = 0; j < 4; j++) r[j] = (a[j] + d[j]) * inv;
      *(f32x4*)&ob2[(size_t)qq * 768 + c * 4] = r;
    }
  }
}

// -------------------------------------------------------------------- launcher
extern "C" void kernel_launch(void* const* d_in, const int* in_sizes, int n_in,
                              void* d_out, int out_size, void* d_ws, size_t ws_size,
                              hipStream_t stream) {
  const float* hs = (const float*)d_in[0];
  const float* Wq = (const float*)d_in[1];
  const float* bq = (const float*)d_in[2];
  const float* Wk = (const float*)d_in[3];
  const float* bk = (const float*)d_in[4];
  const float* Wv = (const float*)d_in[5];
  const float* bv = (const float*)d_in[6];
  float* out = (float*)d_out;

  char* w = (char*)d_ws;
  bf16_t* hsb = (bf16_t*)w; w += (size_t)4096 * 768 * 2;
  bf16_t* wtb = (bf16_t*)w; w += (size_t)2304 * 768 * 2;
  bf16_t* Qb  = (bf16_t*)w; w += (size_t)24 * 2048 * 64 * 2;
  bf16_t* Kb  = (bf16_t*)w; w += (size_t)24 * 2048 * 64 * 2;
  bf16_t* VTb = (bf16_t*)w; w += (size_t)24 * 2048 * 64 * 2;
  float* Opw  = (float*)w;  w += (size_t)2 * 24 * 2048 * 64 * 4;  // 25.2 MB
  float* lpw  = (float*)w;  w += (size_t)2 * 24 * 2048 * 4;       // 0.39 MB
  uint32_t* tkw = (uint32_t*)w;                                   // 1.5 KB

  hipLaunchKernelGGL(cvt, dim3(4800), dim3(256), 0, stream, hs, hsb, Wq, Wk, Wv,
                     wtb, tkw);
  hipLaunchKernelGGL(gemm_qkv, dim3(18, 32), dim3(256), 0, stream, hsb, wtb, bq,
                     bk, bv, Qb, Kb, VTb);
  hipLaunchKernelGGL(attn, dim3(768), dim3(256), 0, stream, Qb, Kb, VTb, Opw,
                     lpw, out, tkw);
}

// Round 11
// 148.677 us; speedup vs baseline: 1.8102x; 1.8102x over previous
//
#include <hip/hip_runtime.h>
#include <stdint.h>

typedef __bf16 bf16_t;
typedef __bf16 bf16x8 __attribute__((ext_vector_type(8)));
typedef float f32x4 __attribute__((ext_vector_type(4)));
typedef float f32x16 __attribute__((ext_vector_type(16)));
typedef unsigned int u32x2 __attribute__((ext_vector_type(2)));

#define DEV __device__ __forceinline__

DEV void gload_lds16(const void* g, void* lds) {
  __builtin_amdgcn_global_load_lds(
      (const __attribute__((address_space(1))) uint32_t*)g,
      (__attribute__((address_space(3))) uint32_t*)lds, 16, 0, 0);
}

DEV float fexp2(float x) {
#if __has_builtin(__builtin_amdgcn_exp2f)
  return __builtin_amdgcn_exp2f(x);
#else
  return exp2f(x);
#endif
}

DEV uint32_t pk_bf16(float a, float b) {
  uint32_t lo = (uint32_t)__builtin_bit_cast(uint16_t, (bf16_t)a);
  uint32_t hi = (uint32_t)__builtin_bit_cast(uint16_t, (bf16_t)b);
  return lo | (hi << 16);
}

// -------------------------------------- K0: merged cvt (hs->bf16, W->WT)
// blocks 0..3071: hs fp32 -> bf16; blocks 3072..4799: W[k][n] (x3) -> WT[n][k]
__global__ __launch_bounds__(256) void cvt(const float* __restrict__ x,
                                           bf16_t* __restrict__ y,
                                           const float* __restrict__ Wq,
                                           const float* __restrict__ Wk,
                                           const float* __restrict__ Wv,
                                           bf16_t* __restrict__ WT) {
  __shared__ float T[32][36];
  const int bid = blockIdx.x;
  const int t = threadIdx.x;
  if (bid < 3072) {
    int i = bid * 256 + t;
    float4 v = ((const float4*)x)[i];
    ((uint2*)y)[i] = make_uint2(pk_bf16(v.x, v.y), pk_bf16(v.z, v.w));
  } else {
    const int b2 = bid - 3072;
    const int bx = b2 % 72;   // n tile 0..71 (over 2304)
    const int by = b2 / 72;   // k tile 0..23 (over 768)
    const int p = bx / 24;
    const float* W = (p == 0) ? Wq : ((p == 1) ? Wk : Wv);
    const int n0 = bx * 32, nn0 = n0 - p * 768, k0 = by * 32;
    {
      int r = t >> 3, c4 = (t & 7) * 4;
      float4 v = *(const float4*)&W[(size_t)(k0 + r) * 768 + nn0 + c4];
      T[r][c4 + 0] = v.x; T[r][c4 + 1] = v.y; T[r][c4 + 2] = v.z; T[r][c4 + 3] = v.w;
    }
    __syncthreads();
    {
      int nr = t >> 3, kc = (t & 7) * 4;
      uint32_t lo = pk_bf16(T[kc + 0][nr], T[kc + 1][nr]);
      uint32_t hi = pk_bf16(T[kc + 2][nr], T[kc + 3][nr]);
      *(uint2*)&WT[(size_t)(n0 + nr) * 768 + k0 + kc] = make_uint2(lo, hi);
    }
  }
}

// ------------------------------------------------- K2: C[4096,2304] = A @ W (+b)
// K-projection output is pre-scaled by log2(e)/8 (softmax scale folded in).
// v5: attn-style 3-buffer counted-vmcnt pipeline. Evidence trail: v2 (BK=64
// dbuf) drains vmcnt(0) at every barrier (the ~20% structural stall) at
// 2 blocks/CU with a 2.25-round dispatch tail; v3 (BK=32, 4 blk/CU, drain-0)
// lost to doubled barrier drains. v5 = v3's verified BK=32 addressing + the
// attn loop shape: stage(kk+2) -> compute(kk) -> vmcnt(4) -> raw s_barrier
// (newest 4-load batch stays in flight; no drain-to-0 in steady state).
// LDS 3x16KB = 48KB (Cs 34816 unions) -> 3 blocks/CU; 576 blocks = one
// fully-resident dispatch round (tail eliminated).
__global__ __launch_bounds__(256) void gemm_qkv(
    const bf16_t* __restrict__ A, const bf16_t* __restrict__ Wt,
    const float* __restrict__ bq, const float* __restrict__ bk,
    const float* __restrict__ bv, bf16_t* __restrict__ Qo,
    bf16_t* __restrict__ Ko, bf16_t* __restrict__ VTo) {
  __shared__ __align__(16) char smem[49152];  // 3 x (As 8K + Bs 8K); Cs union
  bf16_t* Cs = (bf16_t*)smem;  // 128x136 epilogue scratch
  const int bx = blockIdx.x;  // 0..17 (n)
  const int by = blockIdx.y;  // 0..31 (m)
  const int m0 = by * 128, n0 = bx * 128;
  const int tid = threadIdx.x, w = tid >> 6, lane = tid & 63;
  const int mw = (w & 1) * 64, nw = (w >> 1) * 64;
  const int quad = lane >> 4, col = lane & 15;

  f32x4 acc[4][4];
  for (int i = 0; i < 4; i++)
    for (int j = 0; j < 4; j++) acc[i][j] = (f32x4){0.f, 0.f, 0.f, 0.f};

  // staging (round-7-verified): 8 chunks of 1KB per matrix (chunk ci = rows
  // ci*16..+15, 64B wide); wave w stages chunks {2w,2w+1} of A and of B.
  // lane l: row-in-chunk cr = l>>2; pre-swizzled source 16B-slot (l&3)^(cr&3).
  const int cr = lane >> 2;
  const int gcs = (lane & 3) ^ (cr & 3);
  const bf16_t* ag = A + (size_t)(m0 + 2 * w * 16 + cr) * 768 + gcs * 8;
  const bf16_t* bg = Wt + (size_t)(n0 + 2 * w * 16 + cr) * 768 + gcs * 8;

  auto stageg = [&](int kk, int bf) {
    const int k0 = kk * 32;
    bf16_t* dA = (bf16_t*)(smem + bf * 16384) + 2 * w * 512;
    bf16_t* dB = (bf16_t*)(smem + bf * 16384 + 8192) + 2 * w * 512;
#pragma unroll
    for (int i = 0; i < 2; i++) {
      gload_lds16(ag + (size_t)i * 16 * 768 + k0, dA + i * 512);
      gload_lds16(bg + (size_t)i * 16 * 768 + k0, dB + i * 512);
    }
  };

  stageg(0, 0);
  stageg(1, 1);
  asm volatile("s_waitcnt vmcnt(4)" ::: "memory");  // buf0 done; buf1 flying
  __builtin_amdgcn_s_barrier();
  asm volatile("" ::: "memory");

  int bb = 0, rb = 2;
  for (int kk = 0; kk < 24; ++kk) {
    if (kk < 22) stageg(kk + 2, rb);  // 2-deep prefetch, in flight across barriers
    const bf16_t* As = (const bf16_t*)(smem + bb * 16384);
    const bf16_t* Bs = (const bf16_t*)(smem + bb * 16384 + 8192);
    bf16x8 af[4], bfr[4];
#pragma unroll
    for (int mt = 0; mt < 4; ++mt) {
      int row = mw + mt * 16 + col;
      af[mt] = *(const bf16x8*)&As[row * 32 + ((quad ^ (row & 3)) * 8)];
    }
#pragma unroll
    for (int nt = 0; nt < 4; ++nt) {
      int row = nw + nt * 16 + col;
      bfr[nt] = *(const bf16x8*)&Bs[row * 32 + ((quad ^ (row & 3)) * 8)];
    }
    __builtin_amdgcn_s_setprio(1);
#pragma unroll
    for (int mt = 0; mt < 4; ++mt)
#pragma unroll
      for (int nt = 0; nt < 4; ++nt)
        acc[mt][nt] = __builtin_amdgcn_mfma_f32_16x16x32_bf16(
            af[mt], bfr[nt], acc[mt][nt], 0, 0, 0);
    __builtin_amdgcn_s_setprio(0);

    // counted wait: keep newest stage batch (4 loads/wave) in flight
    if (kk < 22) {
      asm volatile("s_waitcnt vmcnt(4)" ::: "memory");
    } else if (kk == 22) {
      asm volatile("s_waitcnt vmcnt(0)" ::: "memory");
    }
    if (kk < 23) {
      __builtin_amdgcn_s_barrier();
      asm volatile("" ::: "memory");
    }
    bb = (bb == 2) ? 0 : bb + 1;
    rb = (rb == 2) ? 0 : rb + 1;
  }
  __syncthreads();  // all waves done reading staging bufs; Cs may overwrite

  const int p = bx / 6;
  const float* bp = (p == 0) ? bq : ((p == 1) ? bk : bv);
  const float kscale = (p == 1) ? 0.18033688011112042f : 1.0f;  // log2(e)/sqrt(64)
  const int bb0 = m0 >> 11, s0 = m0 & 2047;
  if (p < 2) {
#pragma unroll
    for (int nt = 0; nt < 4; nt++) {
      int n = nw + nt * 16 + col;
      float bias = bp[n0 + n - p * 768];
#pragma unroll
      for (int mt = 0; mt < 4; mt++)
#pragma unroll
        for (int r = 0; r < 4; r++) {
          int m = mw + mt * 16 + quad * 4 + r;
          Cs[m * 136 + n] = (bf16_t)((acc[mt][nt][r] + bias) * kscale);
        }
    }
    __syncthreads();
    bf16_t* dst = (p == 0) ? Qo : Ko;
#pragma unroll
    for (int i = 0; i < 8; i++) {
      int idx = i * 256 + tid;
      int m = idx >> 4, c = idx & 15;
      bf16x8 v = *(const bf16x8*)&Cs[m * 136 + c * 8];
      int nn = n0 - p * 768 + c * 8;
      int hq = nn >> 6, hd = nn & 63;
      *(bf16x8*)&dst[(size_t)((bb0 * 12 + hq) * 2048 + s0 + m) * 64 + hd] = v;
    }
  } else {
#pragma unroll
    for (int nt = 0; nt < 4; nt++) {
      int n = nw + nt * 16 + col;
      float bias = bp[n0 + n - 1536];
#pragma unroll
      for (int mt = 0; mt < 4; mt++)
#pragma unroll
        for (int r = 0; r < 4; r++) {
          int m = mw + mt * 16 + quad * 4 + r;
          Cs[n * 136 + m] = (bf16_t)(acc[mt][nt][r] + bias);
        }
    }
    __syncthreads();
#pragma unroll
    for (int i = 0; i < 8; i++) {
      int idx = i * 256 + tid;
      int n = idx >> 4, c = idx & 15;
      bf16x8 v = *(const bf16x8*)&Cs[n * 136 + c * 8];
      int nn = n0 - 1536 + n;
      int hq = nn >> 6, hd = nn & 63;
      *(bf16x8*)&VTo[((size_t)(bb0 * 12 + hq) * 64 + hd) * 2048 + s0 + c * 8] = v;
    }
  }
}

// ---------------------------------------------------------------- K3: attention
// v7 (round-3 best) VERBATIM. Failed variants: ksplit=4 (+HBM traffic, 2x),
// reg-streaming (scatter VMEM, 2.4x), QK-ahead ping-pong (VGPR spill),
// fused combine w/ threadfence (L2 invalidation, 4x). Do not restructure.
__global__ __launch_bounds__(256, 3) void attn(const bf16_t* __restrict__ Q,
                                               const bf16_t* __restrict__ K,
                                               const bf16_t* __restrict__ VT,
                                               float* __restrict__ Op,
                                               float* __restrict__ lp) {
  __shared__ __align__(16) char smem[49152];
  bf16_t* Kl = (bf16_t*)smem;            // [3][64*64], XOR-swizzled by row&7
  bf16_t* Vl = (bf16_t*)(smem + 24576);  // [3][64*64], same swizzle
  const int id = blockIdx.x;             // 0..767
  const int rr0 = id >> 3;               // 0..95
  const int bh = (id & 7) * 3 + (rr0 >> 5);  // XCD id&7 owns 3 consecutive bh
  const int w5 = rr0 & 31;
  const int qt = w5 & 15, sp = w5 >> 4;  // q-tile, key-split half
  const int tid = threadIdx.x, wv = tid >> 6, lane = tid & 63;
  const int lq = lane & 31, half = lane >> 5;
  const int q0 = qt * 128 + wv * 32;

  bf16x8 qf[4];  // B-frags of Q^T (per-lane query = lq), register resident
#pragma unroll
  for (int ks = 0; ks < 4; ++ks)
    qf[ks] = *(const bf16x8*)&Q[(size_t)(bh * 2048 + q0 + lq) * 64 + ks * 16 + half * 8];

  f32x16 oacc[2];  // O^T partial: col=q (lane), rows=d
  for (int i = 0; i < 16; i++) { oacc[0][i] = 0.f; oacc[1][i] = 0.f; }
  float l0 = 0.f, l1 = 0.f, l2 = 0.f, l3 = 0.f;  // partial denominators

  const bf16_t* gK = K + (size_t)bh * 2048 * 64 + (size_t)sp * 1024 * 64;
  const bf16_t* gV = VT + (size_t)bh * 64 * 2048 + sp * 1024;
  const int srow = lane >> 3, scc = lane & 7;
  const int cg = scc ^ srow;  // inverse-swizzled source col (row&7 == srow)
  const bf16_t* gKb = gK + srow * 64 + cg * 8;    // + kb*4096 + ii*512
  const bf16_t* gVb = gV + srow * 2048 + cg * 8;  // + ii*16384 + kb*64
  const int kpart = (wv & 1) * 4;  // waves 0,1 stage K chunks 0-3/4-7; 2,3 V

  auto stage = [&](int kb, int buf) {
    if (wv < 2) {
#pragma unroll
      for (int i = 0; i < 4; i++) {
        int ii = kpart + i;
        gload_lds16(gKb + kb * 4096 + ii * 512, Kl + buf * 4096 + ii * 512);
      }
    } else {
#pragma unroll
      for (int i = 0; i < 4; i++) {
        int ii = kpart + i;
        gload_lds16(gVb + (size_t)ii * 16384 + kb * 64, Vl + buf * 4096 + ii * 512);
      }
    }
  };

  stage(0, 0);
  stage(1, 1);
  asm volatile("s_waitcnt vmcnt(4)" ::: "memory");  // buf0 (+Q) done; buf1 flying
  __builtin_amdgcn_s_barrier();
  asm volatile("" ::: "memory");

  int bb = 0, rb = 2;
  for (int kb = 0; kb < 16; ++kb) {
    if (kb < 14) stage(kb + 2, rb);  // 2-deep prefetch, in flight across barriers

    // S^T[key][q] = K_blk @ Q^T   (K pre-scaled by log2e/8 at projection)
    f32x16 sacc[2];
    for (int i = 0; i < 16; i++) { sacc[0][i] = 0.f; sacc[1][i] = 0.f; }
    __builtin_amdgcn_s_setprio(1);
#pragma unroll
    for (int t = 0; t < 2; t++) {
      const int row = t * 32 + lq;
#pragma unroll
      for (int ks = 0; ks < 4; ++ks) {
        bf16x8 kf = *(const bf16x8*)&Kl[bb * 4096 + row * 64 + (((2 * ks + half) ^ (row & 7)) * 8)];
        sacc[t] = __builtin_amdgcn_mfma_f32_32x32x16_bf16(kf, qf[ks], sacc[t], 0, 0, 0);
      }
    }
    __builtin_amdgcn_s_setprio(0);

    // P = exp2(S) (fixed max), l in 4 partial chains
#pragma unroll
    for (int t = 0; t < 2; t++)
#pragma unroll
      for (int rr = 0; rr < 16; rr++) sacc[t][rr] = fexp2(sacc[t][rr]);
#pragma unroll
    for (int rr = 0; rr < 16; rr += 4) {
      l0 += sacc[0][rr + 0] + sacc[1][rr + 0];
      l1 += sacc[0][rr + 1] + sacc[1][rr + 1];
      l2 += sacc[0][rr + 2] + sacc[1][rr + 2];
      l3 += sacc[0][rr + 3] + sacc[1][rr + 3];
    }

    // pack quads: pkq[t][g] = keys t*32 + 8g + 4*half + {0..3}, as 2x u32
    uint32_t pkq[2][4][2];
#pragma unroll
    for (int t = 0; t < 2; t++)
#pragma unroll
      for (int g = 0; g < 4; g++) {
        pkq[t][g][0] = pk_bf16(sacc[t][4 * g + 0], sacc[t][4 * g + 1]);
        pkq[t][g][1] = pk_bf16(sacc[t][4 * g + 2], sacc[t][4 * g + 3]);
      }

    // cross-half exchange -> B-operand frags via permlane32_swap
    bf16x8 pfrag[4];
#pragma unroll
    for (int t = 0; t < 2; t++)
#pragma unroll
      for (int e = 0; e < 2; e++) {
        union { uint32_t u[4]; bf16x8 v; } F;
#pragma unroll
        for (int wd = 0; wd < 2; wd++) {
#if __has_builtin(__builtin_amdgcn_permlane32_swap)
          u32x2 sw = __builtin_amdgcn_permlane32_swap(pkq[t][2 * e][wd],
                                                      pkq[t][2 * e + 1][wd],
                                                      false, false);
          F.u[wd] = sw.x;
          F.u[2 + wd] = sw.y;
#else
          uint32_t s = half ? pkq[t][2 * e][wd] : pkq[t][2 * e + 1][wd];
          uint32_t rx = __shfl_xor(s, 32);
          uint32_t ow = half ? pkq[t][2 * e + 1][wd] : pkq[t][2 * e][wd];
          F.u[wd] = half ? rx : ow;
          F.u[2 + wd] = half ? ow : rx;
#endif
        }
        pfrag[2 * t + e] = F.v;
      }

    // O^T += V^T @ P^T  (A = V frags from LDS, B = pfrag)
    __builtin_amdgcn_s_setprio(1);
#pragma unroll
    for (int c = 0; c < 4; c++) {
#pragma unroll
      for (int dt = 0; dt < 2; dt++) {
        const int vr = dt * 32 + lq;
        bf16x8 vf = *(const bf16x8*)&Vl[bb * 4096 + vr * 64 + (((2 * c + half) ^ (vr & 7)) * 8)];
        oacc[dt] = __builtin_amdgcn_mfma_f32_32x32x16_bf16(vf, pfrag[c], oacc[dt], 0, 0, 0);
      }
    }
    __builtin_amdgcn_s_setprio(0);

    // counted wait: keep newest stage batch (4 loads/wave) in flight
    if (kb < 14) {
      asm volatile("s_waitcnt vmcnt(4)" ::: "memory");
    } else if (kb == 14) {
      asm volatile("s_waitcnt vmcnt(0)" ::: "memory");
    }
    if (kb < 15) {
      __builtin_amdgcn_s_barrier();
      asm volatile("" ::: "memory");
    }
    bb = (bb == 2) ? 0 : bb + 1;
    rb = (rb == 2) ? 0 : rb + 1;
  }

  // epilogue: partial l + unnormalized partial O^T -> Op[q][d] rows
  float l_own = (l0 + l1) + (l2 + l3);
  float l_tot = l_own + __shfl_xor(l_own, 32);
  __syncthreads();  // all K/V reads done; smem becomes 4x 8KB f32 scratch
  float* Of = (float*)smem + wv * 2048;
#pragma unroll
  for (int dt = 0; dt < 2; dt++)
#pragma unroll
    for (int rr = 0; rr < 16; rr++) {
      int d = dt * 32 + (rr & 3) + 8 * (rr >> 2) + 4 * half;
      int g = d >> 2, wd = d & 3;
      Of[lq * 64 + ((g ^ (lq & 15)) * 4) + wd] = oacc[dt][rr];
    }
  if (half == 0) lp[((size_t)sp * 24 + bh) * 2048 + q0 + lq] = l_tot;
  float* ob = Op + (((size_t)sp * 24 + bh) * 2048 + q0) * 64;
#pragma unroll
  for (int i = 0; i < 8; i++) {
    int idx = i * 64 + lane;
    int qq = idx >> 4, c = idx & 15;
    f32x4 v = *(f32x4*)&Of[qq * 64 + ((c ^ (qq & 15)) * 4)];
    *(f32x4*)&ob[(size_t)qq * 64 + c * 4] = v;
  }
}

// ------------------------------------------------- K4: combine split-K partials
// out[b][q][h*64+d] = (Op0 + Op1) / (l0 + l1), with head-merge transpose.
__global__ __launch_bounds__(256) void combine(const float* __restrict__ Op,
                                               const float* __restrict__ lp,
                                               float* __restrict__ out) {
  int g = blockIdx.x * 256 + threadIdx.x;  // over 24*2048*16 = 786432
  int bh = g >> 15;
  int rem = g & 32767;
  int q = rem >> 4, c = rem & 15;
  const size_t plane = (size_t)24 * 2048 * 64;
  size_t o0 = ((size_t)bh * 2048 + q) * 64 + c * 4;
  f32x4 a = *(const f32x4*)&Op[o0];
  f32x4 b2 = *(const f32x4*)&Op[plane + o0];
  float l = lp[bh * 2048 + q] + lp[24 * 2048 + bh * 2048 + q];
  float inv = 1.0f / l;
  int b = bh / 12, head = bh % 12;
  f32x4 r;
#pragma unroll
  for (int j = 0; j < 4; j++) r[j] = (a[j] + b2[j]) * inv;
  *(f32x4*)&out[((size_t)b * 2048 + q) * 768 + head * 64 + c * 4] = r;
}

// -------------------------------------------------------------------- launcher
extern "C" void kernel_launch(void* const* d_in, const int* in_sizes, int n_in,
                              void* d_out, int out_size, void* d_ws, size_t ws_size,
                              hipStream_t stream) {
  const float* hs = (const float*)d_in[0];
  const float* Wq = (const float*)d_in[1];
  const float* bq = (const float*)d_in[2];
  const float* Wk = (const float*)d_in[3];
  const float* bk = (const float*)d_in[4];
  const float* Wv = (const float*)d_in[5];
  const float* bv = (const float*)d_in[6];
  float* out = (float*)d_out;

  char* w = (char*)d_ws;
  bf16_t* hsb = (bf16_t*)w; w += (size_t)4096 * 768 * 2;
  bf16_t* wtb = (bf16_t*)w; w += (size_t)2304 * 768 * 2;
  bf16_t* Qb  = (bf16_t*)w; w += (size_t)24 * 2048 * 64 * 2;
  bf16_t* Kb  = (bf16_t*)w; w += (size_t)24 * 2048 * 64 * 2;
  bf16_t* VTb = (bf16_t*)w; w += (size_t)24 * 2048 * 64 * 2;
  float* Opw  = (float*)w;  w += (size_t)2 * 24 * 2048 * 64 * 4;  // 25.2 MB
  float* lpw  = (float*)w;                                        // 0.39 MB

  hipLaunchKernelGGL(cvt, dim3(4800), dim3(256), 0, stream, hs, hsb, Wq, Wk, Wv,
                     wtb);
  hipLaunchKernelGGL(gemm_qkv, dim3(18, 32), dim3(256), 0, stream, hsb, wtb, bq,
                     bk, bv, Qb, Kb, VTb);
  hipLaunchKernelGGL(attn, dim3(768), dim3(256), 0, stream, Qb, Kb, VTb, Opw, lpw);
  hipLaunchKernelGGL(combine, dim3(3072), dim3(256), 0, stream, Opw, lpw, out);
}